// Round 8
// baseline (823.496 us; speedup 1.0000x reference)
//
#include <hip/hip_runtime.h>
#include <math.h>

#define BATCH 4
#define CH    48
#define QKVC  144
#define HID   192
#define HEADS 8
#define IMG   256
#define HWSZ  65536

// Allow the register allocator to use up to ~256 VGPRs (min 2 waves/EU)
// instead of the default max-occupancy cap that spills arrays to AGPR/scratch.
#define BIGREG __attribute__((amdgpu_waves_per_eu(2, 8)))

typedef unsigned short bf16u;

__device__ __forceinline__ float lo_f(unsigned u) { return __uint_as_float(u << 16); }
__device__ __forceinline__ float hi_f(unsigned u) { return __uint_as_float(u & 0xffff0000u); }
__device__ __forceinline__ bf16u f2bf(float f) {
    unsigned u = __float_as_uint(f);
    unsigned r = u + 0x7fffu + ((u >> 16) & 1u);
    return (bf16u)(r >> 16);
}
__device__ __forceinline__ unsigned pack2(float a, float b) {
    return (unsigned)f2bf(a) | ((unsigned)f2bf(b) << 16);
}
__device__ __forceinline__ void ld3(const char* rp, unsigned& a, unsigned& b, unsigned& c) {
    a = *(const unsigned*)(rp - 4);
    b = *(const unsigned*)(rp);
    c = *(const unsigned*)(rp + 4);
}

// ---------------------------------------------------------------------------
// K0: transpose w_f2 (48x192) -> w2t (192x48)
// ---------------------------------------------------------------------------
__global__ __launch_bounds__(256) void k0_w2t(const float* __restrict__ w2, float* __restrict__ w2t)
{
    const int e = blockIdx.x * 256 + threadIdx.x;
    if (e < CH * HID) {
        const int o = e / HID, gc = e - o * HID;
        w2t[gc * CH + o] = w2[e];
    }
}

// ---------------------------------------------------------------------------
// K1: per-pixel LN over C=48 + 1x1 conv -> 144 qkv channels (bf16 out).
// ---------------------------------------------------------------------------
__global__ __launch_bounds__(256) BIGREG void k1_ln_qkv(
    const float* __restrict__ x, const float* __restrict__ ln_g, const float* __restrict__ ln_b,
    const float* __restrict__ wq, const float* __restrict__ bq,
    bf16u* __restrict__ qkv)
{
    const int tid = threadIdx.x;
    const int b = blockIdx.x >> 8;
    const int p = ((blockIdx.x & 255) << 8) | tid;
    const float* xb = x + ((size_t)b * CH << 16) + p;
    float y[CH];
    float mu = 0.f;
#pragma unroll
    for (int c = 0; c < CH; ++c) { y[c] = xb[(size_t)c << 16]; mu += y[c]; }
    mu *= (1.0f / CH);
    float var = 0.f;
#pragma unroll
    for (int c = 0; c < CH; ++c) { float d = y[c] - mu; var += d * d; }
    const float rs = rsqrtf(var * (1.0f / CH) + 1e-5f);
#pragma unroll
    for (int c = 0; c < CH; ++c) y[c] = (y[c] - mu) * rs * ln_g[c] + ln_b[c];

    bf16u* qb = qkv + ((size_t)b * QKVC << 16) + p;
#pragma unroll 2
    for (int o = 0; o < QKVC; ++o) {
        float acc = bq[o];
#pragma unroll
        for (int c = 0; c < CH; ++c) acc += wq[o * CH + c] * y[c];
        qb[(size_t)o << 16] = f2bf(acc);
    }
}

// ---------------------------------------------------------------------------
// K2: dw3x3 for one head's 18 channels, 2 px/lane, uint bf16-pair taps.
// ---------------------------------------------------------------------------
__global__ __launch_bounds__(512) BIGREG void k2_dw_gram(
    const bf16u* __restrict__ qkv, const float* __restrict__ wdw, const float* __restrict__ bdw,
    bf16u* __restrict__ vout, float* __restrict__ stats)
{
    __shared__ float red[8][48];
    const int tid = threadIdx.x;
    int blk = blockIdx.x;
    const int tx = blk & 1;  blk >>= 1;
    const int ty = blk & 31; blk >>= 5;
    const int h  = blk & 7;  blk >>= 3;
    const int b  = blk;
    const int lane = tid & 63, wv = tid >> 6;
    const int xg = (tx << 7) | (lane << 1);      // even, 0..254
    const int yg = (ty << 3) | wv;               // wave-uniform
    const bool lE = (xg == 0), rE = (xg == 254);
    const bool r0ok = yg > 0, r2ok = yg < 255;
    const int rowbyte = ((yg << 8) | xg) << 1;

    float q0[6], q1[6], k0a[6], k1a[6];

#pragma unroll
    for (int s = 0; s < 3; ++s) {
#pragma unroll
        for (int j = 0; j < 6; ++j) {
            const int cg = s * 48 + h * 6 + j;
            const char* pb = (const char*)(qkv + ((size_t)(b * QKVC + cg) << 16));
            const char* rp = pb + rowbyte;
            unsigned u0 = 0, u1 = 0, u2 = 0, u3, u4, u5, u6 = 0, u7 = 0, u8 = 0;
            if (r0ok) ld3(rp - 512, u0, u1, u2);
            ld3(rp, u3, u4, u5);
            if (r2ok) ld3(rp + 512, u6, u7, u8);

            const float* w9 = wdw + cg * 9;
            float d0 = bdw[cg], d1 = d0;
#pragma unroll
            for (int r = 0; r < 3; ++r) {
                unsigned a = r == 0 ? u0 : (r == 1 ? u3 : u6);
                unsigned m = r == 0 ? u1 : (r == 1 ? u4 : u7);
                unsigned p = r == 0 ? u2 : (r == 1 ? u5 : u8);
                float vm = lE ? 0.f : hi_f(a);
                float v0 = lo_f(m), v1 = hi_f(m);
                float vr = rE ? 0.f : lo_f(p);
                d0 += w9[r * 3] * vm + w9[r * 3 + 1] * v0 + w9[r * 3 + 2] * v1;
                d1 += w9[r * 3] * v0 + w9[r * 3 + 1] * v1 + w9[r * 3 + 2] * vr;
            }
            if (s == 0)      { q0[j] = d0; q1[j] = d1; }
            else if (s == 1) { k0a[j] = d0; k1a[j] = d1; }
            else {
                char* vp = (char*)(vout + ((size_t)(b * CH + h * 6 + j) << 16));
                *(unsigned*)(vp + rowbyte) = pack2(d0, d1);
            }
        }
    }

    float S[48];
#pragma unroll
    for (int c = 0; c < 6; ++c)
#pragma unroll
        for (int d = 0; d < 6; ++d) S[c * 6 + d] = q0[c] * k0a[d] + q1[c] * k1a[d];
#pragma unroll
    for (int c = 0; c < 6; ++c) {
        S[36 + c] = q0[c] * q0[c] + q1[c] * q1[c];
        S[42 + c] = k0a[c] * k0a[c] + k1a[c] * k1a[c];
    }

#pragma unroll
    for (int i = 0; i < 48; ++i) {
        float r = S[i];
        for (int o = 32; o; o >>= 1) r += __shfl_down(r, o);
        if (lane == 0) red[wv][i] = r;
    }
    __syncthreads();
    if (tid < 48) {
        float s = 0.f;
#pragma unroll
        for (int w = 0; w < 8; ++w) s += red[w][tid];
        atomicAdd(&stats[((size_t)b * HEADS + h) * 48 + tid], s);
    }
}

// ---------------------------------------------------------------------------
// K3: cosine-sim logits -> softmax -> attn; fold with W_proj into M[b] (48x48)
// ---------------------------------------------------------------------------
__global__ __launch_bounds__(256) void k3_attn(
    const float* __restrict__ stats, const float* __restrict__ scale,
    const float* __restrict__ wproj, float* __restrict__ M)
{
    const int b = blockIdx.x;
    __shared__ float attn[HEADS][6][6];
    const int tid = threadIdx.x;
    if (tid < 48) {
        const int h = tid / 6, c = tid - h * 6;
        const float* st = stats + ((size_t)b * HEADS + h) * 48;
        const float qn = fmaxf(sqrtf(st[36 + c]), 1e-12f);
        const float sc = scale[h];
        float s[6]; float mx = -1e30f;
#pragma unroll
        for (int d = 0; d < 6; ++d) {
            const float kn = fmaxf(sqrtf(st[42 + d]), 1e-12f);
            s[d] = st[c * 6 + d] / (qn * kn) * sc;
            mx = fmaxf(mx, s[d]);
        }
        float sum = 0.f;
#pragma unroll
        for (int d = 0; d < 6; ++d) { s[d] = expf(s[d] - mx); sum += s[d]; }
        const float inv = 1.f / sum;
#pragma unroll
        for (int d = 0; d < 6; ++d) attn[h][c][d] = s[d] * inv;
    }
    __syncthreads();
    for (int e = tid; e < 48 * 48; e += 256) {
        const int o = e / 48; const int i = e - o * 48;
        const int h = i / 6,  d = i - h * 6;
        float acc = 0.f;
#pragma unroll
        for (int c = 0; c < 6; ++c) acc += wproj[o * 48 + h * 6 + c] * attn[h][c][d];
        M[(size_t)b * 2304 + e] = acc;
    }
}

// ---------------------------------------------------------------------------
// K45: x1 = x + M_b@v + b_proj (fp32 -> d_out), then LN + 1x1 -> h1 (bf16)
// ---------------------------------------------------------------------------
__global__ __launch_bounds__(256) BIGREG void k45_pvproj_ln_f1(
    const float* __restrict__ x, const bf16u* __restrict__ vbuf,
    const float* __restrict__ M, const float* __restrict__ bproj,
    const float* __restrict__ ln_g, const float* __restrict__ ln_b,
    const float* __restrict__ w1, const float* __restrict__ b1,
    float* __restrict__ x1, bf16u* __restrict__ h1)
{
    const int tid = threadIdx.x;
    const int b = blockIdx.x >> 8;
    const int p = ((blockIdx.x & 255) << 8) | tid;
    const float* Mb = M + (size_t)b * 2304;
    float v[CH];
    const bf16u* vb = vbuf + ((size_t)b * CH << 16) + p;
#pragma unroll
    for (int c = 0; c < CH; ++c) v[c] = lo_f((unsigned)vb[(size_t)c << 16]);
    const float* xb = x + ((size_t)b * CH << 16) + p;
    float* ob = x1 + ((size_t)b * CH << 16) + p;

    float y[CH];
    float mu = 0.f;
    for (int o = 0; o < CH; ++o) {
        float acc = bproj[o];
#pragma unroll
        for (int c = 0; c < CH; ++c) acc += Mb[o * CH + c] * v[c];
        acc += xb[(size_t)o << 16];
        ob[(size_t)o << 16] = acc;
        y[o] = acc; mu += acc;
    }
    mu *= (1.0f / CH);
    float var = 0.f;
#pragma unroll
    for (int c = 0; c < CH; ++c) { float d = y[c] - mu; var += d * d; }
    const float rs = rsqrtf(var * (1.0f / CH) + 1e-5f);
#pragma unroll
    for (int c = 0; c < CH; ++c) y[c] = (y[c] - mu) * rs * ln_g[c] + ln_b[c];

    bf16u* hb = h1 + ((size_t)b * HID << 16) + p;
#pragma unroll 2
    for (int o = 0; o < HID; ++o) {
        float acc = b1[o];
#pragma unroll
        for (int c = 0; c < CH; ++c) acc += w1[o * CH + c] * y[c];
        hb[(size_t)o << 16] = f2bf(acc);
    }
}

// ---------------------------------------------------------------------------
// K6: dw3x3 over all 192 channels + sigmoid-GELU + 1x1 partial (24 of 48
// outputs per block, og-split) + residual. 2 px/lane, hand 2x-unrolled
// channel loop, float2 stores, no atomics.
// ---------------------------------------------------------------------------
__global__ __launch_bounds__(512) BIGREG void k6_ffn2(
    const bf16u* __restrict__ h1, const float* __restrict__ wfdw, const float* __restrict__ bfdw,
    const float* __restrict__ w2t, const float* __restrict__ b2,
    float* __restrict__ xio)
{
    const int tid = threadIdx.x;
    int blk = blockIdx.x;
    const int tx = blk & 1;  blk >>= 1;
    const int ty = blk & 31; blk >>= 5;
    const int og = blk & 1;  blk >>= 1;
    const int b  = blk;
    const int lane = tid & 63, wv = tid >> 6;
    const int xg = (tx << 7) | (lane << 1);
    const int yg = (ty << 3) | wv;               // wave-uniform
    const bool lE = (xg == 0), rE = (xg == 254);
    const bool r0ok = yg > 0, r2ok = yg < 255;
    const int rowbyte = ((yg << 8) | xg) << 1;
    const int o0 = og * 24;

    float a0[24], a1[24];
#pragma unroll
    for (int o = 0; o < 24; ++o) { a0[o] = 0.f; a1[o] = 0.f; }

    for (int gc = 0; gc < HID; gc += 2) {
        // ---- issue BOTH channels' taps before consuming either ----
        const char* rpA = (const char*)(h1 + ((size_t)(b * HID + gc) << 16)) + rowbyte;
        const char* rpB = (const char*)(h1 + ((size_t)(b * HID + gc + 1) << 16)) + rowbyte;
        unsigned A0 = 0, A1 = 0, A2 = 0, A3, A4, A5, A6 = 0, A7 = 0, A8 = 0;
        unsigned B0 = 0, B1 = 0, B2 = 0, B3, B4, B5, B6 = 0, B7 = 0, B8 = 0;
        if (r0ok) { ld3(rpA - 512, A0, A1, A2); ld3(rpB - 512, B0, B1, B2); }
        ld3(rpA, A3, A4, A5);
        ld3(rpB, B3, B4, B5);
        if (r2ok) { ld3(rpA + 512, A6, A7, A8); ld3(rpB + 512, B6, B7, B8); }

#pragma unroll
        for (int cc = 0; cc < 2; ++cc) {
            const int g = gc + cc;
            const unsigned u0 = cc ? B0 : A0, u1 = cc ? B1 : A1, u2 = cc ? B2 : A2;
            const unsigned u3 = cc ? B3 : A3, u4 = cc ? B4 : A4, u5 = cc ? B5 : A5;
            const unsigned u6 = cc ? B6 : A6, u7 = cc ? B7 : A7, u8 = cc ? B8 : A8;
            const float* w9 = wfdw + g * 9;
            float d0 = bfdw[g], d1 = d0;
#pragma unroll
            for (int r = 0; r < 3; ++r) {
                unsigned a = r == 0 ? u0 : (r == 1 ? u3 : u6);
                unsigned m = r == 0 ? u1 : (r == 1 ? u4 : u7);
                unsigned p = r == 0 ? u2 : (r == 1 ? u5 : u8);
                float vm = lE ? 0.f : hi_f(a);
                float v0 = lo_f(m), v1 = hi_f(m);
                float vr = rE ? 0.f : lo_f(p);
                d0 += w9[r * 3] * vm + w9[r * 3 + 1] * v0 + w9[r * 3 + 2] * v1;
                d1 += w9[r * 3] * v0 + w9[r * 3 + 1] * v1 + w9[r * 3 + 2] * vr;
            }
            // sigmoid-GELU: x*sigma(1.702x)  (|err| < 0.005 for |x|<1)
            const float g0 = d0 * __builtin_amdgcn_rcpf(1.f + __expf(-1.702f * d0));
            const float g1 = d1 * __builtin_amdgcn_rcpf(1.f + __expf(-1.702f * d1));
            const float* wr = w2t + g * CH + o0;
#pragma unroll
            for (int o = 0; o < 24; ++o) { a0[o] += wr[o] * g0; a1[o] += wr[o] * g1; }
        }
    }

    float* ob = xio + ((size_t)b * CH << 16) + ((yg << 8) | xg);
#pragma unroll
    for (int o = 0; o < 24; ++o) {
        float2* pp = (float2*)(ob + ((size_t)(o0 + o) << 16));
        float2 r = *pp;
        r.x += a0[o] + b2[o0 + o];
        r.y += a1[o] + b2[o0 + o];
        *pp = r;
    }
}

// ---------------------------------------------------------------------------
extern "C" void kernel_launch(void* const* d_in, const int* in_sizes, int n_in,
                              void* d_out, int out_size, void* d_ws, size_t ws_size,
                              hipStream_t stream)
{
    const float* x      = (const float*)d_in[0];
    const float* ln1_g  = (const float*)d_in[1];
    const float* ln1_b  = (const float*)d_in[2];
    const float* w_qkv  = (const float*)d_in[3];
    const float* b_qkv  = (const float*)d_in[4];
    const float* w_dw   = (const float*)d_in[5];
    const float* b_dw   = (const float*)d_in[6];
    const float* scale  = (const float*)d_in[7];
    const float* w_proj = (const float*)d_in[8];
    const float* b_proj = (const float*)d_in[9];
    const float* ln2_g  = (const float*)d_in[10];
    const float* ln2_b  = (const float*)d_in[11];
    const float* w_f1   = (const float*)d_in[12];
    const float* b_f1   = (const float*)d_in[13];
    const float* w_fdw  = (const float*)d_in[14];
    const float* b_fdw  = (const float*)d_in[15];
    const float* w_f2   = (const float*)d_in[16];
    const float* b_f2   = (const float*)d_in[17];
    float* out = (float*)d_out;

    // Workspace (bytes), 256B guard before qkv/h1 for the x-2 edge loads:
    //   [256)          qkv bf16 (75.5MB) / h1 bf16 (100.66MB)
    //   [100663552)    vbuf bf16 (25.2MB)
    //   [125829376)    stats f32 (1536)
    //   [125835520)    M f32 (9216)
    //   [125872384)    w2t f32 (9216)
    char* wsb = (char*)d_ws;
    bf16u* qkv   = (bf16u*)(wsb + 256);              // also h1
    bf16u* vbuf  = (bf16u*)(wsb + 100663552);
    float* stats = (float*)(wsb + 125829376);
    float* M     = (float*)(wsb + 125835520);
    float* w2t   = (float*)(wsb + 125872384);

    hipMemsetAsync(stats, 0, 1536 * sizeof(float), stream);

    k0_w2t          <<<dim3(36),           dim3(256), 0, stream>>>(w_f2, w2t);
    k1_ln_qkv       <<<dim3(BATCH * 256),  dim3(256), 0, stream>>>(x, ln1_g, ln1_b, w_qkv, b_qkv, qkv);
    k2_dw_gram      <<<dim3(BATCH * HEADS * 64), dim3(512), 0, stream>>>(qkv, w_dw, b_dw, vbuf, stats);
    k3_attn         <<<dim3(BATCH),        dim3(256), 0, stream>>>(stats, scale, w_proj, M);
    k45_pvproj_ln_f1<<<dim3(BATCH * 256),  dim3(256), 0, stream>>>(x, vbuf, M, b_proj,
                                                                   ln2_g, ln2_b, w_f1, b_f1, out, qkv);
    k6_ffn2         <<<dim3(BATCH * 128),  dim3(512), 0, stream>>>(qkv, w_fdw, b_fdw, w2t, b_f2, out);
}

// Round 9
// 788.622 us; speedup vs baseline: 1.0442x; 1.0442x over previous
//
#include <hip/hip_runtime.h>
#include <math.h>

#define BATCH 4
#define CH    48
#define QKVC  144
#define HID   192
#define HEADS 8
#define IMG   256
#define HWSZ  65536

// Neutral per R8 A/B (kept: allows allocator headroom, no measured harm).
#define BIGREG __attribute__((amdgpu_waves_per_eu(2, 8)))

typedef unsigned short bf16u;

__device__ __forceinline__ float lo_f(unsigned u) { return __uint_as_float(u << 16); }
__device__ __forceinline__ float hi_f(unsigned u) { return __uint_as_float(u & 0xffff0000u); }
__device__ __forceinline__ bf16u f2bf(float f) {
    unsigned u = __float_as_uint(f);
    unsigned r = u + 0x7fffu + ((u >> 16) & 1u);
    return (bf16u)(r >> 16);
}
__device__ __forceinline__ unsigned pack2(float a, float b) {
    return (unsigned)f2bf(a) | ((unsigned)f2bf(b) << 16);
}
__device__ __forceinline__ void ld3(const char* rp, unsigned& a, unsigned& b, unsigned& c) {
    a = *(const unsigned*)(rp - 4);
    b = *(const unsigned*)(rp);
    c = *(const unsigned*)(rp + 4);
}

// ---------------------------------------------------------------------------
// K0: transpose w_f2 (48x192) -> w2t (192x48)
// ---------------------------------------------------------------------------
__global__ __launch_bounds__(256) void k0_w2t(const float* __restrict__ w2, float* __restrict__ w2t)
{
    const int e = blockIdx.x * 256 + threadIdx.x;
    if (e < CH * HID) {
        const int o = e / HID, gc = e - o * HID;
        w2t[gc * CH + o] = w2[e];
    }
}

// ---------------------------------------------------------------------------
// K1: per-pixel LN over C=48 + 1x1 conv -> 144 qkv channels (bf16 out).
// ---------------------------------------------------------------------------
__global__ __launch_bounds__(256) BIGREG void k1_ln_qkv(
    const float* __restrict__ x, const float* __restrict__ ln_g, const float* __restrict__ ln_b,
    const float* __restrict__ wq, const float* __restrict__ bq,
    bf16u* __restrict__ qkv)
{
    const int tid = threadIdx.x;
    const int b = blockIdx.x >> 8;
    const int p = ((blockIdx.x & 255) << 8) | tid;
    const float* xb = x + ((size_t)b * CH << 16) + p;
    float y[CH];
    float mu = 0.f;
#pragma unroll
    for (int c = 0; c < CH; ++c) { y[c] = xb[(size_t)c << 16]; mu += y[c]; }
    mu *= (1.0f / CH);
    float var = 0.f;
#pragma unroll
    for (int c = 0; c < CH; ++c) { float d = y[c] - mu; var += d * d; }
    const float rs = rsqrtf(var * (1.0f / CH) + 1e-5f);
#pragma unroll
    for (int c = 0; c < CH; ++c) y[c] = (y[c] - mu) * rs * ln_g[c] + ln_b[c];

    bf16u* qb = qkv + ((size_t)b * QKVC << 16) + p;
#pragma unroll 2
    for (int o = 0; o < QKVC; ++o) {
        float acc = bq[o];
#pragma unroll
        for (int c = 0; c < CH; ++c) acc += wq[o * CH + c] * y[c];
        qb[(size_t)o << 16] = f2bf(acc);
    }
}

// ---------------------------------------------------------------------------
// K2: dw3x3 for one head's 18 channels, 2 px/lane, uint bf16-pair taps.
// ---------------------------------------------------------------------------
__global__ __launch_bounds__(512) BIGREG void k2_dw_gram(
    const bf16u* __restrict__ qkv, const float* __restrict__ wdw, const float* __restrict__ bdw,
    bf16u* __restrict__ vout, float* __restrict__ stats)
{
    __shared__ float red[8][48];
    const int tid = threadIdx.x;
    int blk = blockIdx.x;
    const int tx = blk & 1;  blk >>= 1;
    const int ty = blk & 31; blk >>= 5;
    const int h  = blk & 7;  blk >>= 3;
    const int b  = blk;
    const int lane = tid & 63, wv = tid >> 6;
    const int xg = (tx << 7) | (lane << 1);      // even, 0..254
    const int yg = (ty << 3) | wv;               // wave-uniform
    const bool lE = (xg == 0), rE = (xg == 254);
    const bool r0ok = yg > 0, r2ok = yg < 255;
    const int rowbyte = ((yg << 8) | xg) << 1;

    float q0[6], q1[6], k0a[6], k1a[6];

#pragma unroll
    for (int s = 0; s < 3; ++s) {
#pragma unroll
        for (int j = 0; j < 6; ++j) {
            const int cg = s * 48 + h * 6 + j;
            const char* pb = (const char*)(qkv + ((size_t)(b * QKVC + cg) << 16));
            const char* rp = pb + rowbyte;
            unsigned u0 = 0, u1 = 0, u2 = 0, u3, u4, u5, u6 = 0, u7 = 0, u8 = 0;
            if (r0ok) ld3(rp - 512, u0, u1, u2);
            ld3(rp, u3, u4, u5);
            if (r2ok) ld3(rp + 512, u6, u7, u8);

            const float* w9 = wdw + cg * 9;
            float d0 = bdw[cg], d1 = d0;
#pragma unroll
            for (int r = 0; r < 3; ++r) {
                unsigned a = r == 0 ? u0 : (r == 1 ? u3 : u6);
                unsigned m = r == 0 ? u1 : (r == 1 ? u4 : u7);
                unsigned p = r == 0 ? u2 : (r == 1 ? u5 : u8);
                float vm = lE ? 0.f : hi_f(a);
                float v0 = lo_f(m), v1 = hi_f(m);
                float vr = rE ? 0.f : lo_f(p);
                d0 += w9[r * 3] * vm + w9[r * 3 + 1] * v0 + w9[r * 3 + 2] * v1;
                d1 += w9[r * 3] * v0 + w9[r * 3 + 1] * v1 + w9[r * 3 + 2] * vr;
            }
            if (s == 0)      { q0[j] = d0; q1[j] = d1; }
            else if (s == 1) { k0a[j] = d0; k1a[j] = d1; }
            else {
                char* vp = (char*)(vout + ((size_t)(b * CH + h * 6 + j) << 16));
                *(unsigned*)(vp + rowbyte) = pack2(d0, d1);
            }
        }
    }

    float S[48];
#pragma unroll
    for (int c = 0; c < 6; ++c)
#pragma unroll
        for (int d = 0; d < 6; ++d) S[c * 6 + d] = q0[c] * k0a[d] + q1[c] * k1a[d];
#pragma unroll
    for (int c = 0; c < 6; ++c) {
        S[36 + c] = q0[c] * q0[c] + q1[c] * q1[c];
        S[42 + c] = k0a[c] * k0a[c] + k1a[c] * k1a[c];
    }

#pragma unroll
    for (int i = 0; i < 48; ++i) {
        float r = S[i];
        for (int o = 32; o; o >>= 1) r += __shfl_down(r, o);
        if (lane == 0) red[wv][i] = r;
    }
    __syncthreads();
    if (tid < 48) {
        float s = 0.f;
#pragma unroll
        for (int w = 0; w < 8; ++w) s += red[w][tid];
        atomicAdd(&stats[((size_t)b * HEADS + h) * 48 + tid], s);
    }
}

// ---------------------------------------------------------------------------
// K3: cosine-sim logits -> softmax -> attn; fold with W_proj into M[b] (48x48)
// ---------------------------------------------------------------------------
__global__ __launch_bounds__(256) void k3_attn(
    const float* __restrict__ stats, const float* __restrict__ scale,
    const float* __restrict__ wproj, float* __restrict__ M)
{
    const int b = blockIdx.x;
    __shared__ float attn[HEADS][6][6];
    const int tid = threadIdx.x;
    if (tid < 48) {
        const int h = tid / 6, c = tid - h * 6;
        const float* st = stats + ((size_t)b * HEADS + h) * 48;
        const float qn = fmaxf(sqrtf(st[36 + c]), 1e-12f);
        const float sc = scale[h];
        float s[6]; float mx = -1e30f;
#pragma unroll
        for (int d = 0; d < 6; ++d) {
            const float kn = fmaxf(sqrtf(st[42 + d]), 1e-12f);
            s[d] = st[c * 6 + d] / (qn * kn) * sc;
            mx = fmaxf(mx, s[d]);
        }
        float sum = 0.f;
#pragma unroll
        for (int d = 0; d < 6; ++d) { s[d] = expf(s[d] - mx); sum += s[d]; }
        const float inv = 1.f / sum;
#pragma unroll
        for (int d = 0; d < 6; ++d) attn[h][c][d] = s[d] * inv;
    }
    __syncthreads();
    for (int e = tid; e < 48 * 48; e += 256) {
        const int o = e / 48; const int i = e - o * 48;
        const int h = i / 6,  d = i - h * 6;
        float acc = 0.f;
#pragma unroll
        for (int c = 0; c < 6; ++c) acc += wproj[o * 48 + h * 6 + c] * attn[h][c][d];
        M[(size_t)b * 2304 + e] = acc;
    }
}

// ---------------------------------------------------------------------------
// K45: x1 = x + M_b@v + b_proj (fp32 -> d_out), then LN + 1x1 -> h1 (bf16).
// FULLY unrolled pvproj loop: y[o] writes get compile-time indices so y[]
// stays in registers (runtime-indexed array writes go to scratch — R8 bug:
// 92MB scratch writeback, 9216 scratch loads/thread).
// ---------------------------------------------------------------------------
__global__ __launch_bounds__(256) BIGREG void k45_pvproj_ln_f1(
    const float* __restrict__ x, const bf16u* __restrict__ vbuf,
    const float* __restrict__ M, const float* __restrict__ bproj,
    const float* __restrict__ ln_g, const float* __restrict__ ln_b,
    const float* __restrict__ w1, const float* __restrict__ b1,
    float* __restrict__ x1, bf16u* __restrict__ h1)
{
    const int tid = threadIdx.x;
    const int b = blockIdx.x >> 8;
    const int p = ((blockIdx.x & 255) << 8) | tid;
    const float* Mb = M + (size_t)b * 2304;
    float v[CH];
    const bf16u* vb = vbuf + ((size_t)b * CH << 16) + p;
#pragma unroll
    for (int c = 0; c < CH; ++c) v[c] = lo_f((unsigned)vb[(size_t)c << 16]);
    const float* xb = x + ((size_t)b * CH << 16) + p;
    float* ob = x1 + ((size_t)b * CH << 16) + p;

    float y[CH];
    float mu = 0.f;
#pragma unroll
    for (int o = 0; o < CH; ++o) {
        float acc = bproj[o];
#pragma unroll
        for (int c = 0; c < CH; ++c) acc += Mb[o * CH + c] * v[c];
        acc += xb[(size_t)o << 16];
        ob[(size_t)o << 16] = acc;
        y[o] = acc; mu += acc;
    }
    mu *= (1.0f / CH);
    float var = 0.f;
#pragma unroll
    for (int c = 0; c < CH; ++c) { float d = y[c] - mu; var += d * d; }
    const float rs = rsqrtf(var * (1.0f / CH) + 1e-5f);
#pragma unroll
    for (int c = 0; c < CH; ++c) y[c] = (y[c] - mu) * rs * ln_g[c] + ln_b[c];

    bf16u* hb = h1 + ((size_t)b * HID << 16) + p;
#pragma unroll 2
    for (int o = 0; o < HID; ++o) {
        float acc = b1[o];
#pragma unroll
        for (int c = 0; c < CH; ++c) acc += w1[o * CH + c] * y[c];
        hb[(size_t)o << 16] = f2bf(acc);
    }
}

// ---------------------------------------------------------------------------
// K6: dw3x3 over all 192 channels + sigmoid-GELU + 1x1 partial (24 of 48
// outputs per block, og-split) + residual. 2 px/lane, hand 2x-unrolled
// channel loop, float2 stores, no atomics.
// ---------------------------------------------------------------------------
__global__ __launch_bounds__(512) BIGREG void k6_ffn2(
    const bf16u* __restrict__ h1, const float* __restrict__ wfdw, const float* __restrict__ bfdw,
    const float* __restrict__ w2t, const float* __restrict__ b2,
    float* __restrict__ xio)
{
    const int tid = threadIdx.x;
    int blk = blockIdx.x;
    const int tx = blk & 1;  blk >>= 1;
    const int ty = blk & 31; blk >>= 5;
    const int og = blk & 1;  blk >>= 1;
    const int b  = blk;
    const int lane = tid & 63, wv = tid >> 6;
    const int xg = (tx << 7) | (lane << 1);
    const int yg = (ty << 3) | wv;               // wave-uniform
    const bool lE = (xg == 0), rE = (xg == 254);
    const bool r0ok = yg > 0, r2ok = yg < 255;
    const int rowbyte = ((yg << 8) | xg) << 1;
    const int o0 = og * 24;

    float a0[24], a1[24];
#pragma unroll
    for (int o = 0; o < 24; ++o) { a0[o] = 0.f; a1[o] = 0.f; }

    for (int gc = 0; gc < HID; gc += 2) {
        // ---- issue BOTH channels' taps before consuming either ----
        const char* rpA = (const char*)(h1 + ((size_t)(b * HID + gc) << 16)) + rowbyte;
        const char* rpB = (const char*)(h1 + ((size_t)(b * HID + gc + 1) << 16)) + rowbyte;
        unsigned A0 = 0, A1 = 0, A2 = 0, A3, A4, A5, A6 = 0, A7 = 0, A8 = 0;
        unsigned B0 = 0, B1 = 0, B2 = 0, B3, B4, B5, B6 = 0, B7 = 0, B8 = 0;
        if (r0ok) { ld3(rpA - 512, A0, A1, A2); ld3(rpB - 512, B0, B1, B2); }
        ld3(rpA, A3, A4, A5);
        ld3(rpB, B3, B4, B5);
        if (r2ok) { ld3(rpA + 512, A6, A7, A8); ld3(rpB + 512, B6, B7, B8); }

#pragma unroll
        for (int cc = 0; cc < 2; ++cc) {
            const int g = gc + cc;
            const unsigned u0 = cc ? B0 : A0, u1 = cc ? B1 : A1, u2 = cc ? B2 : A2;
            const unsigned u3 = cc ? B3 : A3, u4 = cc ? B4 : A4, u5 = cc ? B5 : A5;
            const unsigned u6 = cc ? B6 : A6, u7 = cc ? B7 : A7, u8 = cc ? B8 : A8;
            const float* w9 = wfdw + g * 9;
            float d0 = bfdw[g], d1 = d0;
#pragma unroll
            for (int r = 0; r < 3; ++r) {
                unsigned a = r == 0 ? u0 : (r == 1 ? u3 : u6);
                unsigned m = r == 0 ? u1 : (r == 1 ? u4 : u7);
                unsigned p = r == 0 ? u2 : (r == 1 ? u5 : u8);
                float vm = lE ? 0.f : hi_f(a);
                float v0 = lo_f(m), v1 = hi_f(m);
                float vr = rE ? 0.f : lo_f(p);
                d0 += w9[r * 3] * vm + w9[r * 3 + 1] * v0 + w9[r * 3 + 2] * v1;
                d1 += w9[r * 3] * v0 + w9[r * 3 + 1] * v1 + w9[r * 3 + 2] * vr;
            }
            // sigmoid-GELU: x*sigma(1.702x)  (|err| < 0.005 for |x|<1)
            const float g0 = d0 * __builtin_amdgcn_rcpf(1.f + __expf(-1.702f * d0));
            const float g1 = d1 * __builtin_amdgcn_rcpf(1.f + __expf(-1.702f * d1));
            const float* wr = w2t + g * CH + o0;
#pragma unroll
            for (int o = 0; o < 24; ++o) { a0[o] += wr[o] * g0; a1[o] += wr[o] * g1; }
        }
    }

    float* ob = xio + ((size_t)b * CH << 16) + ((yg << 8) | xg);
#pragma unroll
    for (int o = 0; o < 24; ++o) {
        float2* pp = (float2*)(ob + ((size_t)(o0 + o) << 16));
        float2 r = *pp;
        r.x += a0[o] + b2[o0 + o];
        r.y += a1[o] + b2[o0 + o];
        *pp = r;
    }
}

// ---------------------------------------------------------------------------
extern "C" void kernel_launch(void* const* d_in, const int* in_sizes, int n_in,
                              void* d_out, int out_size, void* d_ws, size_t ws_size,
                              hipStream_t stream)
{
    const float* x      = (const float*)d_in[0];
    const float* ln1_g  = (const float*)d_in[1];
    const float* ln1_b  = (const float*)d_in[2];
    const float* w_qkv  = (const float*)d_in[3];
    const float* b_qkv  = (const float*)d_in[4];
    const float* w_dw   = (const float*)d_in[5];
    const float* b_dw   = (const float*)d_in[6];
    const float* scale  = (const float*)d_in[7];
    const float* w_proj = (const float*)d_in[8];
    const float* b_proj = (const float*)d_in[9];
    const float* ln2_g  = (const float*)d_in[10];
    const float* ln2_b  = (const float*)d_in[11];
    const float* w_f1   = (const float*)d_in[12];
    const float* b_f1   = (const float*)d_in[13];
    const float* w_fdw  = (const float*)d_in[14];
    const float* b_fdw  = (const float*)d_in[15];
    const float* w_f2   = (const float*)d_in[16];
    const float* b_f2   = (const float*)d_in[17];
    float* out = (float*)d_out;

    // Workspace (bytes), 256B guard before qkv/h1 for the x-2 edge loads:
    //   [256)          qkv bf16 (75.5MB) / h1 bf16 (100.66MB)
    //   [100663552)    vbuf bf16 (25.2MB)
    //   [125829376)    stats f32 (1536)
    //   [125835520)    M f32 (9216)
    //   [125872384)    w2t f32 (9216)
    char* wsb = (char*)d_ws;
    bf16u* qkv   = (bf16u*)(wsb + 256);              // also h1
    bf16u* vbuf  = (bf16u*)(wsb + 100663552);
    float* stats = (float*)(wsb + 125829376);
    float* M     = (float*)(wsb + 125835520);
    float* w2t   = (float*)(wsb + 125872384);

    hipMemsetAsync(stats, 0, 1536 * sizeof(float), stream);

    k0_w2t          <<<dim3(36),           dim3(256), 0, stream>>>(w_f2, w2t);
    k1_ln_qkv       <<<dim3(BATCH * 256),  dim3(256), 0, stream>>>(x, ln1_g, ln1_b, w_qkv, b_qkv, qkv);
    k2_dw_gram      <<<dim3(BATCH * HEADS * 64), dim3(512), 0, stream>>>(qkv, w_dw, b_dw, vbuf, stats);
    k3_attn         <<<dim3(BATCH),        dim3(256), 0, stream>>>(stats, scale, w_proj, M);
    k45_pvproj_ln_f1<<<dim3(BATCH * 256),  dim3(256), 0, stream>>>(x, vbuf, M, b_proj,
                                                                   ln2_g, ln2_b, w_f1, b_f1, out, qkv);
    k6_ffn2         <<<dim3(BATCH * 128),  dim3(512), 0, stream>>>(qkv, w_fdw, b_fdw, w2t, b_f2, out);
}

// Round 10
// 753.275 us; speedup vs baseline: 1.0932x; 1.0469x over previous
//
#include <hip/hip_runtime.h>
#include <math.h>

#define BATCH 4
#define CH    48
#define QKVC  144
#define HID   192
#define HEADS 8
#define IMG   256
#define HWSZ  65536

// Neutral per R8 A/B (kept: allocator headroom, no measured harm).
#define BIGREG __attribute__((amdgpu_waves_per_eu(2, 8)))

typedef unsigned short bf16u;

__device__ __forceinline__ float lo_f(unsigned u) { return __uint_as_float(u << 16); }
__device__ __forceinline__ float hi_f(unsigned u) { return __uint_as_float(u & 0xffff0000u); }
__device__ __forceinline__ bf16u f2bf(float f) {
    unsigned u = __float_as_uint(f);
    unsigned r = u + 0x7fffu + ((u >> 16) & 1u);
    return (bf16u)(r >> 16);
}
__device__ __forceinline__ unsigned pack2(float a, float b) {
    return (unsigned)f2bf(a) | ((unsigned)f2bf(b) << 16);
}
__device__ __forceinline__ void ld3(const char* rp, unsigned& a, unsigned& b, unsigned& c) {
    a = *(const unsigned*)(rp - 4);
    b = *(const unsigned*)(rp);
    c = *(const unsigned*)(rp + 4);
}

// ---------------------------------------------------------------------------
// K0: transpose w_f2 (48x192) -> w2t (192x48)
// ---------------------------------------------------------------------------
__global__ __launch_bounds__(256) void k0_w2t(const float* __restrict__ w2, float* __restrict__ w2t)
{
    const int e = blockIdx.x * 256 + threadIdx.x;
    if (e < CH * HID) {
        const int o = e / HID, gc = e - o * HID;
        w2t[gc * CH + o] = w2[e];
    }
}

// ---------------------------------------------------------------------------
// K1: per-pixel LN over C=48 + 1x1 conv -> 144 qkv channels (bf16 out).
// R10 experiment: Wq staged in LDS (27.6KB) -> weight reads on LGKM pipe
// with immediate offsets, zero VALU/SGPR cost per access.
// ---------------------------------------------------------------------------
__global__ __launch_bounds__(256) BIGREG void k1_ln_qkv(
    const float* __restrict__ x, const float* __restrict__ ln_g, const float* __restrict__ ln_b,
    const float* __restrict__ wq, const float* __restrict__ bq,
    bf16u* __restrict__ qkv)
{
    __shared__ float sWq[QKVC * CH];          // 27648 B
    const int tid = threadIdx.x;
    for (int i = tid; i < QKVC * CH; i += 256) sWq[i] = wq[i];

    const int b = blockIdx.x >> 8;
    const int p = ((blockIdx.x & 255) << 8) | tid;
    const float* xb = x + ((size_t)b * CH << 16) + p;
    float y[CH];
    float mu = 0.f;
#pragma unroll
    for (int c = 0; c < CH; ++c) { y[c] = xb[(size_t)c << 16]; mu += y[c]; }
    mu *= (1.0f / CH);
    float var = 0.f;
#pragma unroll
    for (int c = 0; c < CH; ++c) { float d = y[c] - mu; var += d * d; }
    const float rs = rsqrtf(var * (1.0f / CH) + 1e-5f);
#pragma unroll
    for (int c = 0; c < CH; ++c) y[c] = (y[c] - mu) * rs * ln_g[c] + ln_b[c];

    __syncthreads();
    bf16u* qb = qkv + ((size_t)b * QKVC << 16) + p;
#pragma unroll 2
    for (int o = 0; o < QKVC; ++o) {
        float acc = bq[o];
#pragma unroll
        for (int c = 0; c < CH; ++c) acc += sWq[o * CH + c] * y[c];
        qb[(size_t)o << 16] = f2bf(acc);
    }
}

// ---------------------------------------------------------------------------
// K2: dw3x3 for one head's 18 channels, 2 px/lane, uint bf16-pair taps.
// (weights tiny per head — unchanged this round)
// ---------------------------------------------------------------------------
__global__ __launch_bounds__(512) BIGREG void k2_dw_gram(
    const bf16u* __restrict__ qkv, const float* __restrict__ wdw, const float* __restrict__ bdw,
    bf16u* __restrict__ vout, float* __restrict__ stats)
{
    __shared__ float red[8][48];
    const int tid = threadIdx.x;
    int blk = blockIdx.x;
    const int tx = blk & 1;  blk >>= 1;
    const int ty = blk & 31; blk >>= 5;
    const int h  = blk & 7;  blk >>= 3;
    const int b  = blk;
    const int lane = tid & 63, wv = tid >> 6;
    const int xg = (tx << 7) | (lane << 1);      // even, 0..254
    const int yg = (ty << 3) | wv;               // wave-uniform
    const bool lE = (xg == 0), rE = (xg == 254);
    const bool r0ok = yg > 0, r2ok = yg < 255;
    const int rowbyte = ((yg << 8) | xg) << 1;

    float q0[6], q1[6], k0a[6], k1a[6];

#pragma unroll
    for (int s = 0; s < 3; ++s) {
#pragma unroll
        for (int j = 0; j < 6; ++j) {
            const int cg = s * 48 + h * 6 + j;
            const char* pb = (const char*)(qkv + ((size_t)(b * QKVC + cg) << 16));
            const char* rp = pb + rowbyte;
            unsigned u0 = 0, u1 = 0, u2 = 0, u3, u4, u5, u6 = 0, u7 = 0, u8 = 0;
            if (r0ok) ld3(rp - 512, u0, u1, u2);
            ld3(rp, u3, u4, u5);
            if (r2ok) ld3(rp + 512, u6, u7, u8);

            const float* w9 = wdw + cg * 9;
            float d0 = bdw[cg], d1 = d0;
#pragma unroll
            for (int r = 0; r < 3; ++r) {
                unsigned a = r == 0 ? u0 : (r == 1 ? u3 : u6);
                unsigned m = r == 0 ? u1 : (r == 1 ? u4 : u7);
                unsigned p = r == 0 ? u2 : (r == 1 ? u5 : u8);
                float vm = lE ? 0.f : hi_f(a);
                float v0 = lo_f(m), v1 = hi_f(m);
                float vr = rE ? 0.f : lo_f(p);
                d0 += w9[r * 3] * vm + w9[r * 3 + 1] * v0 + w9[r * 3 + 2] * v1;
                d1 += w9[r * 3] * v0 + w9[r * 3 + 1] * v1 + w9[r * 3 + 2] * vr;
            }
            if (s == 0)      { q0[j] = d0; q1[j] = d1; }
            else if (s == 1) { k0a[j] = d0; k1a[j] = d1; }
            else {
                char* vp = (char*)(vout + ((size_t)(b * CH + h * 6 + j) << 16));
                *(unsigned*)(vp + rowbyte) = pack2(d0, d1);
            }
        }
    }

    float S[48];
#pragma unroll
    for (int c = 0; c < 6; ++c)
#pragma unroll
        for (int d = 0; d < 6; ++d) S[c * 6 + d] = q0[c] * k0a[d] + q1[c] * k1a[d];
#pragma unroll
    for (int c = 0; c < 6; ++c) {
        S[36 + c] = q0[c] * q0[c] + q1[c] * q1[c];
        S[42 + c] = k0a[c] * k0a[c] + k1a[c] * k1a[c];
    }

#pragma unroll
    for (int i = 0; i < 48; ++i) {
        float r = S[i];
        for (int o = 32; o; o >>= 1) r += __shfl_down(r, o);
        if (lane == 0) red[wv][i] = r;
    }
    __syncthreads();
    if (tid < 48) {
        float s = 0.f;
#pragma unroll
        for (int w = 0; w < 8; ++w) s += red[w][tid];
        atomicAdd(&stats[((size_t)b * HEADS + h) * 48 + tid], s);
    }
}

// ---------------------------------------------------------------------------
// K3: cosine-sim logits -> softmax -> attn; fold with W_proj into M[b] (48x48)
// ---------------------------------------------------------------------------
__global__ __launch_bounds__(256) void k3_attn(
    const float* __restrict__ stats, const float* __restrict__ scale,
    const float* __restrict__ wproj, float* __restrict__ M)
{
    const int b = blockIdx.x;
    __shared__ float attn[HEADS][6][6];
    const int tid = threadIdx.x;
    if (tid < 48) {
        const int h = tid / 6, c = tid - h * 6;
        const float* st = stats + ((size_t)b * HEADS + h) * 48;
        const float qn = fmaxf(sqrtf(st[36 + c]), 1e-12f);
        const float sc = scale[h];
        float s[6]; float mx = -1e30f;
#pragma unroll
        for (int d = 0; d < 6; ++d) {
            const float kn = fmaxf(sqrtf(st[42 + d]), 1e-12f);
            s[d] = st[c * 6 + d] / (qn * kn) * sc;
            mx = fmaxf(mx, s[d]);
        }
        float sum = 0.f;
#pragma unroll
        for (int d = 0; d < 6; ++d) { s[d] = expf(s[d] - mx); sum += s[d]; }
        const float inv = 1.f / sum;
#pragma unroll
        for (int d = 0; d < 6; ++d) attn[h][c][d] = s[d] * inv;
    }
    __syncthreads();
    for (int e = tid; e < 48 * 48; e += 256) {
        const int o = e / 48; const int i = e - o * 48;
        const int h = i / 6,  d = i - h * 6;
        float acc = 0.f;
#pragma unroll
        for (int c = 0; c < 6; ++c) acc += wproj[o * 48 + h * 6 + c] * attn[h][c][d];
        M[(size_t)b * 2304 + e] = acc;
    }
}

// ---------------------------------------------------------------------------
// K45: x1 = x + M_b@v + b_proj (fp32 -> d_out), then LN + 1x1 -> h1 (bf16).
// R10 experiment: M_b (9.2KB) + W1 (36.9KB) staged in LDS.
// ---------------------------------------------------------------------------
__global__ __launch_bounds__(256) BIGREG void k45_pvproj_ln_f1(
    const float* __restrict__ x, const bf16u* __restrict__ vbuf,
    const float* __restrict__ M, const float* __restrict__ bproj,
    const float* __restrict__ ln_g, const float* __restrict__ ln_b,
    const float* __restrict__ w1, const float* __restrict__ b1,
    float* __restrict__ x1, bf16u* __restrict__ h1)
{
    __shared__ float sM[CH * CH];             // 9216 B
    __shared__ float sW1[HID * CH];           // 36864 B
    const int tid = threadIdx.x;
    const int b = blockIdx.x >> 8;
    const float* Mb = M + (size_t)b * 2304;
    for (int i = tid; i < CH * CH; i += 256) sM[i] = Mb[i];
    for (int i = tid; i < HID * CH; i += 256) sW1[i] = w1[i];

    const int p = ((blockIdx.x & 255) << 8) | tid;
    float v[CH];
    const bf16u* vb = vbuf + ((size_t)b * CH << 16) + p;
#pragma unroll
    for (int c = 0; c < CH; ++c) v[c] = lo_f((unsigned)vb[(size_t)c << 16]);
    const float* xb = x + ((size_t)b * CH << 16) + p;
    float* ob = x1 + ((size_t)b * CH << 16) + p;

    __syncthreads();
    float y[CH];
    float mu = 0.f;
#pragma unroll
    for (int o = 0; o < CH; ++o) {
        float acc = bproj[o];
#pragma unroll
        for (int c = 0; c < CH; ++c) acc += sM[o * CH + c] * v[c];
        acc += xb[(size_t)o << 16];
        ob[(size_t)o << 16] = acc;
        y[o] = acc; mu += acc;
    }
    mu *= (1.0f / CH);
    float var = 0.f;
#pragma unroll
    for (int c = 0; c < CH; ++c) { float d = y[c] - mu; var += d * d; }
    const float rs = rsqrtf(var * (1.0f / CH) + 1e-5f);
#pragma unroll
    for (int c = 0; c < CH; ++c) y[c] = (y[c] - mu) * rs * ln_g[c] + ln_b[c];

    bf16u* hb = h1 + ((size_t)b * HID << 16) + p;
#pragma unroll 2
    for (int o = 0; o < HID; ++o) {
        float acc = b1[o];
#pragma unroll
        for (int c = 0; c < CH; ++c) acc += sW1[o * CH + c] * y[c];
        hb[(size_t)o << 16] = f2bf(acc);
    }
}

// ---------------------------------------------------------------------------
// K6: dw3x3 over all 192 channels + sigmoid-GELU + 1x1 partial (24 of 48
// outputs per block, og-split) + residual. 2 px/lane, hand 2x-unrolled
// channel loop, float2 stores, no atomics.
// R10 experiment: w2t half (18.4KB) + wfdw (6.9KB) + bfdw staged in LDS.
// ---------------------------------------------------------------------------
__global__ __launch_bounds__(512) BIGREG void k6_ffn2(
    const bf16u* __restrict__ h1, const float* __restrict__ wfdw, const float* __restrict__ bfdw,
    const float* __restrict__ w2t, const float* __restrict__ b2,
    float* __restrict__ xio)
{
    __shared__ float sW2[HID * 24];           // 18432 B (this block's 24 outputs)
    __shared__ float sW9[HID * 9];            // 6912 B
    __shared__ float sBf[HID];                // 768 B
    const int tid = threadIdx.x;
    int blk = blockIdx.x;
    const int tx = blk & 1;  blk >>= 1;
    const int ty = blk & 31; blk >>= 5;
    const int og = blk & 1;  blk >>= 1;
    const int b  = blk;
    const int o0 = og * 24;

    for (int i = tid; i < HID * 24; i += 512) {
        const int g = i / 24, o = i - g * 24;
        sW2[i] = w2t[g * CH + o0 + o];
    }
    for (int i = tid; i < HID * 9; i += 512) sW9[i] = wfdw[i];
    for (int i = tid; i < HID; i += 512) sBf[i] = bfdw[i];
    __syncthreads();

    const int lane = tid & 63, wv = tid >> 6;
    const int xg = (tx << 7) | (lane << 1);
    const int yg = (ty << 3) | wv;               // wave-uniform
    const bool lE = (xg == 0), rE = (xg == 254);
    const bool r0ok = yg > 0, r2ok = yg < 255;
    const int rowbyte = ((yg << 8) | xg) << 1;

    float a0[24], a1[24];
#pragma unroll
    for (int o = 0; o < 24; ++o) { a0[o] = 0.f; a1[o] = 0.f; }

    for (int gc = 0; gc < HID; gc += 2) {
        // ---- issue BOTH channels' taps before consuming either ----
        const char* rpA = (const char*)(h1 + ((size_t)(b * HID + gc) << 16)) + rowbyte;
        const char* rpB = (const char*)(h1 + ((size_t)(b * HID + gc + 1) << 16)) + rowbyte;
        unsigned A0 = 0, A1 = 0, A2 = 0, A3, A4, A5, A6 = 0, A7 = 0, A8 = 0;
        unsigned B0 = 0, B1 = 0, B2 = 0, B3, B4, B5, B6 = 0, B7 = 0, B8 = 0;
        if (r0ok) { ld3(rpA - 512, A0, A1, A2); ld3(rpB - 512, B0, B1, B2); }
        ld3(rpA, A3, A4, A5);
        ld3(rpB, B3, B4, B5);
        if (r2ok) { ld3(rpA + 512, A6, A7, A8); ld3(rpB + 512, B6, B7, B8); }

#pragma unroll
        for (int cc = 0; cc < 2; ++cc) {
            const int g = gc + cc;
            const unsigned u0 = cc ? B0 : A0, u1 = cc ? B1 : A1, u2 = cc ? B2 : A2;
            const unsigned u3 = cc ? B3 : A3, u4 = cc ? B4 : A4, u5 = cc ? B5 : A5;
            const unsigned u6 = cc ? B6 : A6, u7 = cc ? B7 : A7, u8 = cc ? B8 : A8;
            const float* w9 = sW9 + g * 9;
            float d0 = sBf[g], d1 = d0;
#pragma unroll
            for (int r = 0; r < 3; ++r) {
                unsigned a = r == 0 ? u0 : (r == 1 ? u3 : u6);
                unsigned m = r == 0 ? u1 : (r == 1 ? u4 : u7);
                unsigned p = r == 0 ? u2 : (r == 1 ? u5 : u8);
                float vm = lE ? 0.f : hi_f(a);
                float v0 = lo_f(m), v1 = hi_f(m);
                float vr = rE ? 0.f : lo_f(p);
                d0 += w9[r * 3] * vm + w9[r * 3 + 1] * v0 + w9[r * 3 + 2] * v1;
                d1 += w9[r * 3] * v0 + w9[r * 3 + 1] * v1 + w9[r * 3 + 2] * vr;
            }
            // sigmoid-GELU: x*sigma(1.702x)  (|err| < 0.005 for |x|<1)
            const float g0 = d0 * __builtin_amdgcn_rcpf(1.f + __expf(-1.702f * d0));
            const float g1 = d1 * __builtin_amdgcn_rcpf(1.f + __expf(-1.702f * d1));
            const float* wr = sW2 + g * 24;
#pragma unroll
            for (int o = 0; o < 24; ++o) { a0[o] += wr[o] * g0; a1[o] += wr[o] * g1; }
        }
    }

    float* ob = xio + ((size_t)b * CH << 16) + ((yg << 8) | xg);
#pragma unroll
    for (int o = 0; o < 24; ++o) {
        float2* pp = (float2*)(ob + ((size_t)(o0 + o) << 16));
        float2 r = *pp;
        r.x += a0[o] + b2[o0 + o];
        r.y += a1[o] + b2[o0 + o];
        *pp = r;
    }
}

// ---------------------------------------------------------------------------
extern "C" void kernel_launch(void* const* d_in, const int* in_sizes, int n_in,
                              void* d_out, int out_size, void* d_ws, size_t ws_size,
                              hipStream_t stream)
{
    const float* x      = (const float*)d_in[0];
    const float* ln1_g  = (const float*)d_in[1];
    const float* ln1_b  = (const float*)d_in[2];
    const float* w_qkv  = (const float*)d_in[3];
    const float* b_qkv  = (const float*)d_in[4];
    const float* w_dw   = (const float*)d_in[5];
    const float* b_dw   = (const float*)d_in[6];
    const float* scale  = (const float*)d_in[7];
    const float* w_proj = (const float*)d_in[8];
    const float* b_proj = (const float*)d_in[9];
    const float* ln2_g  = (const float*)d_in[10];
    const float* ln2_b  = (const float*)d_in[11];
    const float* w_f1   = (const float*)d_in[12];
    const float* b_f1   = (const float*)d_in[13];
    const float* w_fdw  = (const float*)d_in[14];
    const float* b_fdw  = (const float*)d_in[15];
    const float* w_f2   = (const float*)d_in[16];
    const float* b_f2   = (const float*)d_in[17];
    float* out = (float*)d_out;

    // Workspace (bytes), 256B guard before qkv/h1 for the x-2 edge loads:
    //   [256)          qkv bf16 (75.5MB) / h1 bf16 (100.66MB)
    //   [100663552)    vbuf bf16 (25.2MB)
    //   [125829376)    stats f32 (1536)
    //   [125835520)    M f32 (9216)
    //   [125872384)    w2t f32 (9216)
    char* wsb = (char*)d_ws;
    bf16u* qkv   = (bf16u*)(wsb + 256);              // also h1
    bf16u* vbuf  = (bf16u*)(wsb + 100663552);
    float* stats = (float*)(wsb + 125829376);
    float* M     = (float*)(wsb + 125835520);
    float* w2t   = (float*)(wsb + 125872384);

    hipMemsetAsync(stats, 0, 1536 * sizeof(float), stream);

    k0_w2t          <<<dim3(36),           dim3(256), 0, stream>>>(w_f2, w2t);
    k1_ln_qkv       <<<dim3(BATCH * 256),  dim3(256), 0, stream>>>(x, ln1_g, ln1_b, w_qkv, b_qkv, qkv);
    k2_dw_gram      <<<dim3(BATCH * HEADS * 64), dim3(512), 0, stream>>>(qkv, w_dw, b_dw, vbuf, stats);
    k3_attn         <<<dim3(BATCH),        dim3(256), 0, stream>>>(stats, scale, w_proj, M);
    k45_pvproj_ln_f1<<<dim3(BATCH * 256),  dim3(256), 0, stream>>>(x, vbuf, M, b_proj,
                                                                   ln2_g, ln2_b, w_f1, b_f1, out, qkv);
    k6_ffn2         <<<dim3(BATCH * 128),  dim3(512), 0, stream>>>(qkv, w_fdw, b_fdw, w2t, b_f2, out);
}